// Round 1
// baseline (1258.647 us; speedup 1.0000x reference)
//
#include <hip/hip_runtime.h>

#define N_NODES 100000
#define N_EDGES 3200000
#define HID 64

// Workspace layout (floats):
//  [0,N)            s1   (layer-1 scalar aggregate)      - zeroed
//  [N,2N)           s3   (layer-3 scalar aggregate)      - zeroed
//  [2N,66N)         agg2 (layer-2 64-dim aggregate)      - zeroed
//  [66N,67N)        p    (h2 . W3_rel per node)
//  [67N,68N)        r    (h2 . W3_root per node)

// ---------- scalar edge aggregation: out[dst] += val[src]*ew ----------
__global__ void edge_agg_scalar(const int* __restrict__ src, const int* __restrict__ dst,
                                const float* __restrict__ ew, const float* __restrict__ val,
                                float* __restrict__ out) {
    int e = blockIdx.x * blockDim.x + threadIdx.x;
    if (e < N_EDGES) {
        atomicAdd(&out[dst[e]], val[src[e]] * ew[e]);
    }
}

// ---------- layer-2 edge aggregation, h1 recomputed on the fly ----------
// thread (e,f): agg2[dst[e]*64+f] += ew[e] * relu(s1[src]*W1_rel[f] + x[src]*W1_root[f] + b1[f])
__global__ __launch_bounds__(256) void edge_agg_l2(
        const int* __restrict__ src, const int* __restrict__ dst,
        const float* __restrict__ ew,
        const float* __restrict__ s1, const float* __restrict__ x,
        const float* __restrict__ W1_rel, const float* __restrict__ W1_root,
        const float* __restrict__ b1,
        float* __restrict__ agg2) {
    const long long total = (long long)N_EDGES * HID;
    const int f = threadIdx.x & 63;
    // f is invariant across grid-stride iterations (stride % 64 == 0)
    const float wr = W1_rel[f];
    const float wt = W1_root[f];
    const float bb = b1[f];
    const long long stride = (long long)gridDim.x * blockDim.x;
    for (long long idx = (long long)blockIdx.x * blockDim.x + threadIdx.x;
         idx < total; idx += stride) {
        const int e = (int)(idx >> 6);
        const int s = src[e];           // broadcast load (same addr across wave)
        const int d = dst[e];
        const float w = ew[e];
        const float h = fmaxf(0.f, fmaf(s1[s], wr, fmaf(x[s], wt, bb)));
        atomicAdd(&agg2[(long long)d * HID + f], h * w);
    }
}

// ---------- node-level: h2 = relu(agg2@W2_rel + h1@W2_root + b2); p=h2.W3_rel; r=h2.W3_root ----------
__global__ __launch_bounds__(256) void node_l2l3(
        const float* __restrict__ s1, const float* __restrict__ x,
        const float* __restrict__ W1_rel, const float* __restrict__ W1_root,
        const float* __restrict__ b1,
        const float* __restrict__ agg2,
        const float* __restrict__ W2_rel, const float* __restrict__ b2,
        const float* __restrict__ W2_root,
        const float* __restrict__ W3_rel, const float* __restrict__ W3_root,
        float* __restrict__ p, float* __restrict__ r) {
    __shared__ float lWrel[HID * HID];
    __shared__ float lWroot[HID * HID];
    for (int t = threadIdx.x; t < HID * HID; t += 256) {
        lWrel[t]  = W2_rel[t];
        lWroot[t] = W2_root[t];
    }
    __syncthreads();

    const int f = threadIdx.x & 63;
    const int wave = threadIdx.x >> 6;              // 0..3
    const int wavesTotal = gridDim.x * 4;
    const float w1r = W1_rel[f], w1t = W1_root[f], bb1 = b1[f];
    const float w3r = W3_rel[f], w3t = W3_root[f], bb2 = b2[f];

    for (int i = blockIdx.x * 4 + wave; i < N_NODES; i += wavesTotal) {
        const float a = agg2[(long long)i * HID + f];
        const float h = fmaxf(0.f, fmaf(s1[i], w1r, fmaf(x[i], w1t, bb1)));
        float acc = bb2;
        #pragma unroll
        for (int k = 0; k < HID; ++k) {
            const float ak = __shfl(a, k, 64);
            const float hk = __shfl(h, k, 64);
            acc = fmaf(ak, lWrel[k * HID + f], acc);
            acc = fmaf(hk, lWroot[k * HID + f], acc);
        }
        const float h2 = fmaxf(0.f, acc);
        float pv = h2 * w3r;
        float rv = h2 * w3t;
        #pragma unroll
        for (int off = 32; off > 0; off >>= 1) {
            pv += __shfl_down(pv, off, 64);
            rv += __shfl_down(rv, off, 64);
        }
        if (f == 0) { p[i] = pv; r[i] = rv; }
    }
}

// ---------- finalize: out = s3 + r + b3 ----------
__global__ void finalize(const float* __restrict__ s3, const float* __restrict__ r,
                         const float* __restrict__ b3, float* __restrict__ out) {
    int i = blockIdx.x * blockDim.x + threadIdx.x;
    if (i < N_NODES) out[i] = s3[i] + r[i] + b3[0];
}

extern "C" void kernel_launch(void* const* d_in, const int* in_sizes, int n_in,
                              void* d_out, int out_size, void* d_ws, size_t ws_size,
                              hipStream_t stream) {
    const float* x      = (const float*)d_in[0];
    const int*   ei     = (const int*)  d_in[1];   // [2, E] flat, int32
    const float* ew     = (const float*)d_in[2];
    const float* W1_rel = (const float*)d_in[3];
    const float* b1     = (const float*)d_in[4];
    const float* W1_root= (const float*)d_in[5];
    const float* W2_rel = (const float*)d_in[6];
    const float* b2     = (const float*)d_in[7];
    const float* W2_root= (const float*)d_in[8];
    const float* W3_rel = (const float*)d_in[9];
    const float* b3     = (const float*)d_in[10];
    const float* W3_root= (const float*)d_in[11];

    const int* src = ei;
    const int* dst = ei + N_EDGES;

    float* ws   = (float*)d_ws;
    float* s1   = ws;
    float* s3   = ws + N_NODES;
    float* agg2 = ws + 2 * (size_t)N_NODES;
    float* p    = ws + (2 + HID) * (size_t)N_NODES;
    float* r    = p + N_NODES;

    // zero s1, s3, agg2 (contiguous prefix of ws)
    hipMemsetAsync(ws, 0, (size_t)(2 + HID) * N_NODES * sizeof(float), stream);

    const int eb = (N_EDGES + 255) / 256;
    edge_agg_scalar<<<eb, 256, 0, stream>>>(src, dst, ew, x, s1);

    edge_agg_l2<<<8192, 256, 0, stream>>>(src, dst, ew, s1, x, W1_rel, W1_root, b1, agg2);

    node_l2l3<<<4096, 256, 0, stream>>>(s1, x, W1_rel, W1_root, b1,
                                        agg2, W2_rel, b2, W2_root,
                                        W3_rel, W3_root, p, r);

    edge_agg_scalar<<<eb, 256, 0, stream>>>(src, dst, ew, p, s3);

    finalize<<<(N_NODES + 255) / 256, 256, 0, stream>>>(s3, r, b3, (float*)d_out);
}

// Round 2
// 853.218 us; speedup vs baseline: 1.4752x; 1.4752x over previous
//
#include <hip/hip_runtime.h>

#define NN 100000
#define NE 3200000
#define HID 64

// -------- CSR build: count --------
__global__ void k_count(const int* __restrict__ dst, int* __restrict__ deg) {
    int e = blockIdx.x * blockDim.x + threadIdx.x;
    if (e < NE) atomicAdd(&deg[dst[e]], 1);
}

// -------- CSR build: per-block exclusive scan (1024/block) --------
__global__ void k_scan_block(const int* __restrict__ deg, int* __restrict__ base,
                             int* __restrict__ blksum) {
    __shared__ int sh[1024];
    const int tid = threadIdx.x;
    const int i = blockIdx.x * 1024 + tid;
    int v = (i < NN) ? deg[i] : 0;
    sh[tid] = v;
    __syncthreads();
    #pragma unroll
    for (int off = 1; off < 1024; off <<= 1) {
        int t = (tid >= off) ? sh[tid - off] : 0;
        __syncthreads();
        sh[tid] += t;
        __syncthreads();
    }
    if (i < NN) base[i] = sh[tid] - v;          // local exclusive
    if (tid == 1023) blksum[blockIdx.x] = sh[1023];
}

// -------- CSR build: scan the 98 block sums (single block) --------
__global__ void k_scan_top(int* __restrict__ blksum, int nb) {
    __shared__ int sh[128];
    const int tid = threadIdx.x;
    int v = (tid < nb) ? blksum[tid] : 0;
    sh[tid] = v;
    __syncthreads();
    #pragma unroll
    for (int off = 1; off < 128; off <<= 1) {
        int t = (tid >= off) ? sh[tid - off] : 0;
        __syncthreads();
        sh[tid] += t;
        __syncthreads();
    }
    if (tid < nb) blksum[tid] = sh[tid] - v;    // exclusive
}

// -------- CSR build: add block offsets; init cursor=base --------
__global__ void k_scan_add(const int* __restrict__ blksum, int* __restrict__ base,
                           int* __restrict__ cursor) {
    int i = blockIdx.x * blockDim.x + threadIdx.x;
    if (i < NN) {
        int b = base[i] + blksum[i >> 10];
        base[i] = b;
        cursor[i] = b;
    }
}

// -------- CSR build: scatter (src, w) records sorted by dst --------
__global__ void k_scatter(const int* __restrict__ src, const int* __restrict__ dst,
                          const float* __restrict__ ew, int* __restrict__ cursor,
                          int2* __restrict__ rec) {
    int e = blockIdx.x * blockDim.x + threadIdx.x;
    if (e < NE) {
        int d = dst[e];
        int pos = atomicAdd(&cursor[d], 1);
        rec[pos] = make_int2(src[e], __float_as_int(ew[e]));
    }
}

// -------- scalar CSR gather: out[i] = sum w*val[src] (+ radd[i] + b[0]) --------
__global__ __launch_bounds__(256) void k_gather_scalar(
        const int* __restrict__ base, const int* __restrict__ endp,
        const int2* __restrict__ rec, const float* __restrict__ val,
        const float* __restrict__ radd, const float* __restrict__ bias,
        float* __restrict__ out) {
    const int i = (blockIdx.x * blockDim.x + threadIdx.x) >> 6;
    const int lane = threadIdx.x & 63;
    if (i >= NN) return;
    const int beg = base[i], end = endp[i];
    float acc = 0.f;
    for (int e = beg + lane; e < end; e += 64) {
        int2 rc = rec[e];                       // coalesced within segment
        acc = fmaf(__int_as_float(rc.y), val[rc.x], acc);
    }
    #pragma unroll
    for (int off = 32; off; off >>= 1) acc += __shfl_down(acc, off, 64);
    if (lane == 0) {
        float o = acc;
        if (radd) o += radd[i] + bias[0];
        out[i] = o;
    }
}

// -------- fused: layer-2 gather (h1 recomputed per edge, acc in regs) +
//          h2 = relu(acc@W2_rel + h1@W2_root + b2); p = h2.W3_rel; r = h2.W3_root --------
__global__ __launch_bounds__(256) void k_l2_fused(
        const int* __restrict__ base, const int* __restrict__ endp,
        const int2* __restrict__ rec,
        const float* __restrict__ s1, const float* __restrict__ x,
        const float* __restrict__ W1_rel, const float* __restrict__ W1_root,
        const float* __restrict__ b1,
        const float* __restrict__ W2_rel, const float* __restrict__ b2,
        const float* __restrict__ W2_root,
        const float* __restrict__ W3_rel, const float* __restrict__ W3_root,
        float* __restrict__ p, float* __restrict__ r) {
    __shared__ float lWrel[HID * HID];
    __shared__ float lWroot[HID * HID];
    for (int t = threadIdx.x; t < HID * HID; t += 256) {
        lWrel[t] = W2_rel[t];
        lWroot[t] = W2_root[t];
    }
    __syncthreads();

    const int f = threadIdx.x & 63;
    const int i = (blockIdx.x * blockDim.x + threadIdx.x) >> 6;   // one node per wave
    if (i >= NN) return;

    const float w1r = W1_rel[f], w1t = W1_root[f], b1f = b1[f];

    float acc = 0.f;
    const int beg = base[i];
    const int cnt = endp[i] - beg;
    for (int c = 0; c < cnt; c += 64) {
        int2 rc = make_int2(0, 0);
        if (c + f < cnt) rc = rec[beg + c + f];   // batched coalesced load
        const int kmax = min(64, cnt - c);
        for (int k = 0; k < kmax; ++k) {
            const int s = __shfl(rc.x, k, 64);                // uniform k -> readlane
            const float w = __shfl(__int_as_float(rc.y), k, 64);
            const float h = fmaxf(0.f, fmaf(s1[s], w1r, fmaf(x[s], w1t, b1f)));
            acc = fmaf(w, h, acc);                            // w=0 for pad lanes
        }
    }

    const float hi = fmaxf(0.f, fmaf(s1[i], w1r, fmaf(x[i], w1t, b1f)));
    float o = b2[f];
    #pragma unroll
    for (int k = 0; k < HID; ++k) {
        o = fmaf(__shfl(acc, k, 64), lWrel[k * HID + f], o);
        o = fmaf(__shfl(hi, k, 64), lWroot[k * HID + f], o);
    }
    const float h2 = fmaxf(0.f, o);

    float pv = h2 * W3_rel[f];
    float rv = h2 * W3_root[f];
    #pragma unroll
    for (int off = 32; off; off >>= 1) {
        pv += __shfl_down(pv, off, 64);
        rv += __shfl_down(rv, off, 64);
    }
    if (f == 0) { p[i] = pv; r[i] = rv; }
}

extern "C" void kernel_launch(void* const* d_in, const int* in_sizes, int n_in,
                              void* d_out, int out_size, void* d_ws, size_t ws_size,
                              hipStream_t stream) {
    const float* x       = (const float*)d_in[0];
    const int*   ei      = (const int*)  d_in[1];
    const float* ew      = (const float*)d_in[2];
    const float* W1_rel  = (const float*)d_in[3];
    const float* b1      = (const float*)d_in[4];
    const float* W1_root = (const float*)d_in[5];
    const float* W2_rel  = (const float*)d_in[6];
    const float* b2      = (const float*)d_in[7];
    const float* W2_root = (const float*)d_in[8];
    const float* W3_rel  = (const float*)d_in[9];
    const float* b3      = (const float*)d_in[10];
    const float* W3_root = (const float*)d_in[11];

    const int* src = ei;
    const int* dst = ei + NE;

    // workspace layout (ints):
    //  deg    [0, NN)        -- reused as p (float) after scans
    //  base   [NN, 2NN)
    //  cursor [2NN, 3NN)
    //  blksum [3NN, 3NN+256)
    //  s1     [3NN+256, 4NN+256)   (float)
    //  r      [4NN+256, 5NN+256)   (float)
    //  rec    [5NN+256, 5NN+256+2NE)  (int2, 8B-aligned)
    int* iws    = (int*)d_ws;
    int* deg    = iws;
    int* base   = iws + NN;
    int* cursor = iws + 2 * NN;
    int* blksum = iws + 3 * NN;
    float* s1   = (float*)(iws + 3 * NN + 256);
    float* r    = s1 + NN;
    int2* rec   = (int2*)(r + NN);
    float* p    = (float*)deg;                   // overlay: deg dead after scans

    hipMemsetAsync(deg, 0, (size_t)NN * sizeof(int), stream);

    const int eb = (NE + 255) / 256;
    const int nb1 = (NN + 1023) / 1024;          // 98
    const int wb = (NN * 64) / 256;              // 25000 blocks, 1 wave/node

    k_count<<<eb, 256, 0, stream>>>(dst, deg);
    k_scan_block<<<nb1, 1024, 0, stream>>>(deg, base, blksum);
    k_scan_top<<<1, 128, 0, stream>>>(blksum, nb1);
    k_scan_add<<<(NN + 255) / 256, 256, 0, stream>>>(blksum, base, cursor);
    k_scatter<<<eb, 256, 0, stream>>>(src, dst, ew, cursor, rec);
    // after scatter: cursor[i] == segment end for node i

    k_gather_scalar<<<wb, 256, 0, stream>>>(base, cursor, rec, x,
                                            nullptr, nullptr, s1);

    k_l2_fused<<<wb, 256, 0, stream>>>(base, cursor, rec, s1, x,
                                       W1_rel, W1_root, b1,
                                       W2_rel, b2, W2_root,
                                       W3_rel, W3_root, p, r);

    k_gather_scalar<<<wb, 256, 0, stream>>>(base, cursor, rec, p,
                                            r, b3, (float*)d_out);
}